// Round 17
// baseline (401.880 us; speedup 1.0000x reference)
//
#include <hip/hip_runtime.h>

constexpr int cB = 4, cC = 64, cH = 128, cW = 128;
constexpr int cL = 4096;   // 64*64
constexpr int cD = 192, cN = 16;
constexpr int NCH = 128, CHUNK = 32;   // cL = NCH*CHUNK

__device__ __forceinline__ float silu_f(float v) { return v / (1.f + __expf(-v)); }

// ---------------------------------------------------------------- K1: Haar DWT + scales
__global__ __launch_bounds__(256) void k_wt(const float* __restrict__ x,
                                            const float* __restrict__ wls,
                                            const float* __restrict__ whs,
                                            float* __restrict__ lraw,
                                            float* __restrict__ high) {
    int idx = blockIdx.x * 256 + threadIdx.x;          // B*C*L = 1,048,576
    int j = idx & 63, i = (idx >> 6) & 63, c = (idx >> 12) & 63, b = idx >> 18;
    const float* xp = x + (((size_t)(b * cC + c)) * cH + 2 * i) * cW + 2 * j;
    float x00 = xp[0], x01 = xp[1], x10 = xp[cW], x11 = xp[cW + 1];
    float s0 = 0.5f * (x00 + x01 + x10 + x11);
    float s1 = 0.5f * (x00 + x01 - x10 - x11);
    float s2 = 0.5f * (x00 - x01 + x10 - x11);
    float s3 = 0.5f * (x00 - x01 - x10 + x11);
    int l = i * 64 + j;
    lraw[(size_t)(b * cC + c) * cL + l] = s0 * wls[c];
    int ch = c * 3;
    high[(size_t)(b * cD + ch + 0) * cL + l] = s1 * whs[ch + 0];
    high[(size_t)(b * cD + ch + 1) * cL + l] = s2 * whs[ch + 1];
    high[(size_t)(b * cD + ch + 2) * cL + l] = s3 * whs[ch + 2];
}

// ---------------------------------------------------------------- K2: low 1x1 conv + silu -> (b,l,c), 4x4 register tile
__global__ __launch_bounds__(256) void k_lowconv(const float* __restrict__ lraw,
                                                 const float* __restrict__ w,
                                                 float* __restrict__ lowT) {
    int bid = blockIdx.x;                 // B*64
    int lt0 = (bid & 63) * 64;
    int b = bid >> 6;
    __shared__ float sW[16][68];
    __shared__ float sI[16][68];
    int tid = threadIdx.x;
    int tl = tid & 15, te = tid >> 4;
    float acc[4][4];
#pragma unroll
    for (int i = 0; i < 4; i++)
#pragma unroll
        for (int j = 0; j < 4; j++) acc[i][j] = 0.f;
    for (int c0 = 0; c0 < 64; c0 += 16) {
#pragma unroll
        for (int q = 0; q < 4; q++) {
            int tt = tid + q * 256;
            int cc = tt & 15, ee = tt >> 4;
            sW[cc][ee] = w[ee * 64 + c0 + cc];
        }
#pragma unroll
        for (int q = 0; q < 4; q++) {
            int tt = tid + q * 256;
            int ll = tt & 63, cc = tt >> 6;
            sI[cc][ll] = lraw[(size_t)(b * cC + c0 + cc) * cL + lt0 + ll];
        }
        __syncthreads();
#pragma unroll
        for (int cc = 0; cc < 16; cc++) {
            float4 wv = *reinterpret_cast<const float4*>(&sW[cc][te * 4]);
            float4 iv = *reinterpret_cast<const float4*>(&sI[cc][tl * 4]);
            acc[0][0] = fmaf(wv.x, iv.x, acc[0][0]); acc[0][1] = fmaf(wv.x, iv.y, acc[0][1]);
            acc[0][2] = fmaf(wv.x, iv.z, acc[0][2]); acc[0][3] = fmaf(wv.x, iv.w, acc[0][3]);
            acc[1][0] = fmaf(wv.y, iv.x, acc[1][0]); acc[1][1] = fmaf(wv.y, iv.y, acc[1][1]);
            acc[1][2] = fmaf(wv.y, iv.z, acc[1][2]); acc[1][3] = fmaf(wv.y, iv.w, acc[1][3]);
            acc[2][0] = fmaf(wv.z, iv.x, acc[2][0]); acc[2][1] = fmaf(wv.z, iv.y, acc[2][1]);
            acc[2][2] = fmaf(wv.z, iv.z, acc[2][2]); acc[2][3] = fmaf(wv.z, iv.w, acc[2][3]);
            acc[3][0] = fmaf(wv.w, iv.x, acc[3][0]); acc[3][1] = fmaf(wv.w, iv.y, acc[3][1]);
            acc[3][2] = fmaf(wv.w, iv.z, acc[3][2]); acc[3][3] = fmaf(wv.w, iv.w, acc[3][3]);
        }
        __syncthreads();
    }
    int ebase = te * 4;
    int lbase = lt0 + tl * 4;
#pragma unroll
    for (int j = 0; j < 4; j++) {
        float4 v = make_float4(silu_f(acc[0][j]), silu_f(acc[1][j]), silu_f(acc[2][j]), silu_f(acc[3][j]));
        *reinterpret_cast<float4*>(&lowT[((size_t)b * cL + lbase + j) * 64 + ebase]) = v;
    }
}

// ---------------------------------------------------------------- K3: in_proj GEMM 384x192, 4x4 register tile
__global__ __launch_bounds__(256) void k_inproj(const float* __restrict__ hi,
                                                const float* __restrict__ w,
                                                float* __restrict__ xout,
                                                float* __restrict__ zT) {
    int bid = blockIdx.x;                  // (b*64+lt)*6 + et
    int et = bid % 6;
    int blt = bid / 6;
    int lt0 = (blt & 63) * 64;
    int b = blt >> 6;
    int e0 = et * 64;
    __shared__ float sW[16][68];
    __shared__ float sI[16][68];
    int tid = threadIdx.x;
    int tl = tid & 15, te = tid >> 4;
    float acc[4][4];
#pragma unroll
    for (int i = 0; i < 4; i++)
#pragma unroll
        for (int j = 0; j < 4; j++) acc[i][j] = 0.f;
    for (int c0 = 0; c0 < 192; c0 += 16) {
#pragma unroll
        for (int q = 0; q < 4; q++) {
            int tt = tid + q * 256;
            int cc = tt & 15, ee = tt >> 4;
            sW[cc][ee] = w[(e0 + ee) * 192 + c0 + cc];
        }
#pragma unroll
        for (int q = 0; q < 4; q++) {
            int tt = tid + q * 256;
            int ll = tt & 63, cc = tt >> 6;
            sI[cc][ll] = hi[(size_t)(b * cD + c0 + cc) * cL + lt0 + ll];
        }
        __syncthreads();
#pragma unroll
        for (int cc = 0; cc < 16; cc++) {
            float4 wv = *reinterpret_cast<const float4*>(&sW[cc][te * 4]);
            float4 iv = *reinterpret_cast<const float4*>(&sI[cc][tl * 4]);
            acc[0][0] = fmaf(wv.x, iv.x, acc[0][0]); acc[0][1] = fmaf(wv.x, iv.y, acc[0][1]);
            acc[0][2] = fmaf(wv.x, iv.z, acc[0][2]); acc[0][3] = fmaf(wv.x, iv.w, acc[0][3]);
            acc[1][0] = fmaf(wv.y, iv.x, acc[1][0]); acc[1][1] = fmaf(wv.y, iv.y, acc[1][1]);
            acc[1][2] = fmaf(wv.y, iv.z, acc[1][2]); acc[1][3] = fmaf(wv.y, iv.w, acc[1][3]);
            acc[2][0] = fmaf(wv.z, iv.x, acc[2][0]); acc[2][1] = fmaf(wv.z, iv.y, acc[2][1]);
            acc[2][2] = fmaf(wv.z, iv.z, acc[2][2]); acc[2][3] = fmaf(wv.z, iv.w, acc[2][3]);
            acc[3][0] = fmaf(wv.w, iv.x, acc[3][0]); acc[3][1] = fmaf(wv.w, iv.y, acc[3][1]);
            acc[3][2] = fmaf(wv.w, iv.z, acc[3][2]); acc[3][3] = fmaf(wv.w, iv.w, acc[3][3]);
        }
        __syncthreads();
    }
    int ebase = e0 + te * 4;
    int lbase = lt0 + tl * 4;
    if (ebase < 192) {
#pragma unroll
        for (int i = 0; i < 4; i++) {
            *reinterpret_cast<float4*>(&xout[(size_t)(b * cD + ebase + i) * cL + lbase]) =
                make_float4(acc[i][0], acc[i][1], acc[i][2], acc[i][3]);
        }
    } else {
#pragma unroll
        for (int j = 0; j < 4; j++) {
            *reinterpret_cast<float4*>(&zT[((size_t)b * cL + lbase + j) * 192 + (ebase - 192)]) =
                make_float4(acc[0][j], acc[1][j], acc[2][j], acc[3][j]);
        }
    }
}

// ---------------------------------------------------------------- K4: dw conv 3x3 + bias + silu; emits x1 and transpose u1
__global__ __launch_bounds__(256) void k_dwconv(const float* __restrict__ xin,
                                                const float* __restrict__ w,
                                                const float* __restrict__ bias,
                                                float* __restrict__ x1,
                                                float* __restrict__ u1) {
    int bd = blockIdx.x;                   // B*D = 768
    int d = bd % cD;
    const float* xp = xin + (size_t)bd * cL;
    float wv[9];
#pragma unroll
    for (int t = 0; t < 9; t++) wv[t] = w[d * 9 + t];
    float bv = bias[d];
    __shared__ float sm[64][65];
    int tid = threadIdx.x;
#pragma unroll
    for (int q = 0; q < 16; q++) {
        int p = tid + q * 256;
        int i = p >> 6, j = p & 63;
        float acc = bv;
#pragma unroll
        for (int di = 0; di < 3; di++) {
            int ii = i + di - 1;
            if (ii < 0 || ii >= 64) continue;
#pragma unroll
            for (int dj = 0; dj < 3; dj++) {
                int jj = j + dj - 1;
                if (jj < 0 || jj >= 64) continue;
                acc = fmaf(wv[di * 3 + dj], xp[ii * 64 + jj], acc);
            }
        }
        sm[i][j] = silu_f(acc);
    }
    __syncthreads();
#pragma unroll
    for (int q = 0; q < 16; q++) {
        int p = tid + q * 256;
        x1[(size_t)bd * cL + p] = sm[p >> 6][p & 63];
        u1[(size_t)bd * cL + p] = sm[p & 63][p >> 6];
    }
}

// ---------------------------------------------------------------- K5: x_proj GEMM (38x192 per direction), 4x4 register tile
__global__ __launch_bounds__(256) void k_xproj(const float* __restrict__ x1,
                                               const float* __restrict__ u1,
                                               const float* __restrict__ xpw,
                                               float* __restrict__ xdbl) {
    int bid = blockIdx.x;                 // B*4*64
    int lt0 = (bid & 63) * 64;
    int k = (bid >> 6) & 3;
    int b = bid >> 8;
    const float* src = (k & 1) ? u1 : x1;
    bool rev = (k >= 2);
    __shared__ float sW[16][68];
    __shared__ float sI[16][68];
    int tid = threadIdx.x;
    int tl = tid & 15, te = tid >> 4;
    float acc[4][4];
#pragma unroll
    for (int i = 0; i < 4; i++)
#pragma unroll
        for (int j = 0; j < 4; j++) acc[i][j] = 0.f;
    for (int c0 = 0; c0 < 192; c0 += 16) {
#pragma unroll
        for (int q = 0; q < 4; q++) {
            int tt = tid + q * 256;
            int cc = tt & 15, ee = tt >> 4;
            sW[cc][ee] = (ee < 38) ? xpw[(k * 38 + ee) * 192 + c0 + cc] : 0.f;
        }
#pragma unroll
        for (int q = 0; q < 4; q++) {
            int tt = tid + q * 256;
            int ll = tt & 63, cc = tt >> 6;
            int l = lt0 + ll;
            int lm = rev ? (cL - 1 - l) : l;
            sI[cc][ll] = src[(size_t)(b * cD + c0 + cc) * cL + lm];
        }
        __syncthreads();
#pragma unroll
        for (int cc = 0; cc < 16; cc++) {
            float4 wv = *reinterpret_cast<const float4*>(&sW[cc][te * 4]);
            float4 iv = *reinterpret_cast<const float4*>(&sI[cc][tl * 4]);
            acc[0][0] = fmaf(wv.x, iv.x, acc[0][0]); acc[0][1] = fmaf(wv.x, iv.y, acc[0][1]);
            acc[0][2] = fmaf(wv.x, iv.z, acc[0][2]); acc[0][3] = fmaf(wv.x, iv.w, acc[0][3]);
            acc[1][0] = fmaf(wv.y, iv.x, acc[1][0]); acc[1][1] = fmaf(wv.y, iv.y, acc[1][1]);
            acc[1][2] = fmaf(wv.y, iv.z, acc[1][2]); acc[1][3] = fmaf(wv.y, iv.w, acc[1][3]);
            acc[2][0] = fmaf(wv.z, iv.x, acc[2][0]); acc[2][1] = fmaf(wv.z, iv.y, acc[2][1]);
            acc[2][2] = fmaf(wv.z, iv.z, acc[2][2]); acc[2][3] = fmaf(wv.z, iv.w, acc[2][3]);
            acc[3][0] = fmaf(wv.w, iv.x, acc[3][0]); acc[3][1] = fmaf(wv.w, iv.y, acc[3][1]);
            acc[3][2] = fmaf(wv.w, iv.z, acc[3][2]); acc[3][3] = fmaf(wv.w, iv.w, acc[3][3]);
        }
        __syncthreads();
    }
    int lbase = lt0 + tl * 4;
#pragma unroll
    for (int i = 0; i < 4; i++) {
        int e = te * 4 + i;
        if (e < 38) {
            *reinterpret_cast<float4*>(&xdbl[(size_t)((b * 4 + k) * 38 + e) * cL + lbase]) =
                make_float4(acc[i][0], acc[i][1], acc[i][2], acc[i][3]);
        }
    }
}

// ---------------------------------------------------------------- K6a: scan pass 1 — lean dbuf, u in regs, scalar Q out
__global__ __launch_bounds__(192) void k_scan1(const float* __restrict__ xdbl,
                                               const float* __restrict__ x1,
                                               const float* __restrict__ u1,
                                               const float* __restrict__ dtw,
                                               const float* __restrict__ dtb,
                                               const float* __restrict__ alog,
                                               float* __restrict__ Qb,
                                               float* __restrict__ S) {
    int bid = blockIdx.x;                  // bk*NCH + ch, 2048 blocks
    int ch = bid % NCH;
    int bk = bid / NCH;
    int k = bk & 3, b = bk >> 2;
    int tid = threadIdx.x;
    int d = tid;                           // 0..191
    float Av2[16], h[16];
#pragma unroll
    for (int j = 0; j < 16; j++) {
        Av2[j] = -__expf(alog[(k * 192 + d) * 16 + j]) * 1.44269504088896f;
        h[j] = 0.f;
    }
    float dtbv = dtb[k * 192 + d];
    float dtwv[6];
#pragma unroll
    for (int r = 0; r < 6; r++) dtwv[r] = dtw[(k * 192 + d) * 6 + r];
    const float* dtrows = xdbl + (size_t)(bk * 38) * cL;
    const float* Brow = xdbl + (size_t)(bk * 38 + 6) * cL;
    const float* ubase = ((k & 1) ? u1 : x1) + ((size_t)b * cD + d) * cL;
    bool rev = (k >= 2);

    __shared__ float sB[2][16][16];   // [buf][l][n]
    __shared__ float sdt[2][16][8];   // [buf][l][r]

    int rowA = tid >> 4, colA = tid & 15;
    int p0 = ch * CHUNK;

    // stage tile 0
    for (int idx = tid; idx < 256; idx += 192)
        sB[0][idx & 15][idx >> 4] = Brow[(size_t)(idx >> 4) * cL + p0 + (idx & 15)];
    if (tid < 96) sdt[0][colA][rowA] = dtrows[(size_t)rowA * cL + p0 + colA];

    float Q = 0.f;
    int cur = 0;
    for (int t0 = p0; t0 < p0 + CHUNK; t0 += 16) {
        __syncthreads();
        if (t0 + 16 < p0 + CHUNK) {
            int t1 = t0 + 16;
            for (int idx = tid; idx < 256; idx += 192)
                sB[cur ^ 1][idx & 15][idx >> 4] = Brow[(size_t)(idx >> 4) * cL + t1 + (idx & 15)];
            if (tid < 96) sdt[cur ^ 1][colA][rowA] = dtrows[(size_t)rowA * cL + t1 + colA];
        }
        // u tile -> registers (contiguous 64B)
        float uvals[16];
        {
            const float* up = rev ? (ubase + (cL - 16 - t0)) : (ubase + t0);
#pragma unroll
            for (int q = 0; q < 4; q++)
                *reinterpret_cast<float4*>(&uvals[q * 4]) = *reinterpret_cast<const float4*>(up + q * 4);
        }
#pragma unroll
        for (int l = 0; l < 16; l++) {
            float acc = dtbv;
#pragma unroll
            for (int r = 0; r < 6; r++) acc = fmaf(dtwv[r], sdt[cur][l][r], acc);
            float sp = fmaxf(acc, 0.f) + __logf(1.f + __expf(-fabsf(acc)));
            Q += sp;
            float uv = rev ? uvals[15 - l] : uvals[l];
            float duB = sp * uv;
            float Bv[16];
            *reinterpret_cast<float4*>(&Bv[0])  = *reinterpret_cast<const float4*>(&sB[cur][l][0]);
            *reinterpret_cast<float4*>(&Bv[4])  = *reinterpret_cast<const float4*>(&sB[cur][l][4]);
            *reinterpret_cast<float4*>(&Bv[8])  = *reinterpret_cast<const float4*>(&sB[cur][l][8]);
            *reinterpret_cast<float4*>(&Bv[12]) = *reinterpret_cast<const float4*>(&sB[cur][l][12]);
#pragma unroll
            for (int j = 0; j < 16; j++)
                h[j] = fmaf(h[j], exp2f(sp * Av2[j]), duB * Bv[j]);
        }
        cur ^= 1;
    }
    size_t base = (size_t)bid * 16 * 192 + d;
#pragma unroll
    for (int j = 0; j < 16; j++) S[base + (size_t)j * 192] = h[j];
    Qb[(size_t)bid * 192 + d] = Q;
}

// ---------------------------------------------------------------- K6b: carry prefix over chunks (decay from Q, in-place in S)
__global__ __launch_bounds__(256) void k_carryQ(const float* __restrict__ alog,
                                                const float* __restrict__ Qb,
                                                float* __restrict__ S) {
    int gid = blockIdx.x * 256 + threadIdx.x;  // 49152 = 16bk * 16n * 192d
    int d = gid % 192;
    int n = (gid / 192) & 15;
    int bk = gid / 3072;
    int k = bk & 3;
    float Av2 = -__expf(alog[(k * 192 + d) * 16 + n]) * 1.44269504088896f;
    float h = 0.f;
    for (int c = 0; c < NCH; c++) {
        size_t qidx = (size_t)(bk * NCH + c) * 192 + d;
        size_t idx = ((size_t)(bk * NCH + c) * 16 + n) * 192 + d;
        h = fmaf(exp2f(Av2 * Qb[qidx]), h, S[idx]);
        S[idx] = h;
    }
}

// ---------------------------------------------------------------- K6c: scan pass 2 — lean replay, y -> atomic combine
__global__ __launch_bounds__(192) void k_scan2(const float* __restrict__ xdbl,
                                               const float* __restrict__ x1,
                                               const float* __restrict__ u1,
                                               const float* __restrict__ dtw,
                                               const float* __restrict__ dtb,
                                               const float* __restrict__ alog,
                                               const float* __restrict__ dss,
                                               const float* __restrict__ S,
                                               float* __restrict__ yacc) {
    int bid = blockIdx.x;
    int ch = bid % NCH;
    int bk = bid / NCH;
    int k = bk & 3, b = bk >> 2;
    int tid = threadIdx.x;
    int d = tid;
    float Av2[16], h[16];
#pragma unroll
    for (int j = 0; j < 16; j++) {
        Av2[j] = -__expf(alog[(k * 192 + d) * 16 + j]) * 1.44269504088896f;
        h[j] = (ch == 0) ? 0.f : S[((size_t)(bk * NCH + ch - 1) * 16 + j) * 192 + d];
    }
    float Dv = dss[k * 192 + d];
    float dtbv = dtb[k * 192 + d];
    float dtwv[6];
#pragma unroll
    for (int r = 0; r < 6; r++) dtwv[r] = dtw[(k * 192 + d) * 6 + r];
    const float* dtrows = xdbl + (size_t)(bk * 38) * cL;
    const float* Brow = xdbl + (size_t)(bk * 38 + 6) * cL;
    const float* Crow = xdbl + (size_t)(bk * 38 + 22) * cL;
    const float* ubase = ((k & 1) ? u1 : x1) + ((size_t)b * cD + d) * cL;
    bool rev = (k >= 2);

    __shared__ float sB[2][16][16];
    __shared__ float sC[2][16][16];
    __shared__ float sdt[2][16][8];

    int rowA = tid >> 4, colA = tid & 15;
    int p0 = ch * CHUNK;

    for (int idx = tid; idx < 256; idx += 192) {
        sB[0][idx & 15][idx >> 4] = Brow[(size_t)(idx >> 4) * cL + p0 + (idx & 15)];
        sC[0][idx & 15][idx >> 4] = Crow[(size_t)(idx >> 4) * cL + p0 + (idx & 15)];
    }
    if (tid < 96) sdt[0][colA][rowA] = dtrows[(size_t)rowA * cL + p0 + colA];

    int cur = 0;
    for (int t0 = p0; t0 < p0 + CHUNK; t0 += 16) {
        __syncthreads();
        if (t0 + 16 < p0 + CHUNK) {
            int t1 = t0 + 16;
            for (int idx = tid; idx < 256; idx += 192) {
                sB[cur ^ 1][idx & 15][idx >> 4] = Brow[(size_t)(idx >> 4) * cL + t1 + (idx & 15)];
                sC[cur ^ 1][idx & 15][idx >> 4] = Crow[(size_t)(idx >> 4) * cL + t1 + (idx & 15)];
            }
            if (tid < 96) sdt[cur ^ 1][colA][rowA] = dtrows[(size_t)rowA * cL + t1 + colA];
        }
        float uvals[16];
        {
            const float* up = rev ? (ubase + (cL - 16 - t0)) : (ubase + t0);
#pragma unroll
            for (int q = 0; q < 4; q++)
                *reinterpret_cast<float4*>(&uvals[q * 4]) = *reinterpret_cast<const float4*>(up + q * 4);
        }
#pragma unroll
        for (int l = 0; l < 16; l++) {
            float acc = dtbv;
#pragma unroll
            for (int r = 0; r < 6; r++) acc = fmaf(dtwv[r], sdt[cur][l][r], acc);
            float sp = fmaxf(acc, 0.f) + __logf(1.f + __expf(-fabsf(acc)));
            float uv = rev ? uvals[15 - l] : uvals[l];
            float duB = sp * uv;
            float Bv[16], Cv[16];
            *reinterpret_cast<float4*>(&Bv[0])  = *reinterpret_cast<const float4*>(&sB[cur][l][0]);
            *reinterpret_cast<float4*>(&Bv[4])  = *reinterpret_cast<const float4*>(&sB[cur][l][4]);
            *reinterpret_cast<float4*>(&Bv[8])  = *reinterpret_cast<const float4*>(&sB[cur][l][8]);
            *reinterpret_cast<float4*>(&Bv[12]) = *reinterpret_cast<const float4*>(&sB[cur][l][12]);
            *reinterpret_cast<float4*>(&Cv[0])  = *reinterpret_cast<const float4*>(&sC[cur][l][0]);
            *reinterpret_cast<float4*>(&Cv[4])  = *reinterpret_cast<const float4*>(&sC[cur][l][4]);
            *reinterpret_cast<float4*>(&Cv[8])  = *reinterpret_cast<const float4*>(&sC[cur][l][8]);
            *reinterpret_cast<float4*>(&Cv[12]) = *reinterpret_cast<const float4*>(&sC[cur][l][12]);
            float yA = 0.f, yB = 0.f;
#pragma unroll
            for (int j = 0; j < 8; j++) {
                h[j] = fmaf(h[j], exp2f(sp * Av2[j]), duB * Bv[j]);
                yA = fmaf(h[j], Cv[j], yA);
            }
#pragma unroll
            for (int j = 8; j < 16; j++) {
                h[j] = fmaf(h[j], exp2f(sp * Av2[j]), duB * Bv[j]);
                yB = fmaf(h[j], Cv[j], yB);
            }
            float y = yA + yB + uv * Dv;
            int lg = t0 + l;
            int lm;
            if (k == 0) lm = lg;
            else if (k == 1) lm = (lg & 63) * 64 + (lg >> 6);
            else if (k == 2) lm = cL - 1 - lg;
            else { int qq = cL - 1 - lg; lm = (qq & 63) * 64 + (qq >> 6); }
            atomicAdd(&yacc[((size_t)b * cL + lm) * 192 + d], y);
        }
        cur ^= 1;
    }
}

// ---------------------------------------------------------------- K7: out_norm LN + silu(z)
__global__ __launch_bounds__(256) void k_comb(const float* __restrict__ yacc,
                                              const float* __restrict__ zT,
                                              const float* __restrict__ ons,
                                              const float* __restrict__ onb,
                                              float* __restrict__ yln) {
    int bid = blockIdx.x;                  // B*1024
    int b = bid >> 10;
    int pg = bid & 1023;
    int tid = threadIdx.x;
    int wq = tid >> 6, lane = tid & 63;
    int l = pg * 4 + wq;
    float v[3];
    float s = 0.f, s2 = 0.f;
#pragma unroll
    for (int m = 0; m < 3; m++) {
        int d = lane + 64 * m;
        float t = yacc[((size_t)b * cL + l) * 192 + d];
        v[m] = t;
        s += t;
        s2 += t * t;
    }
#pragma unroll
    for (int o = 1; o < 64; o <<= 1) {
        s += __shfl_xor(s, o);
        s2 += __shfl_xor(s2, o);
    }
    float mean = s / 192.f;
    float var = s2 / 192.f - mean * mean;
    float rstd = rsqrtf(var + 1e-5f);
#pragma unroll
    for (int m = 0; m < 3; m++) {
        int d = lane + 64 * m;
        float zv = zT[((size_t)b * cL + l) * 192 + d];
        float yn = (v[m] - mean) * rstd * ons[d] + onb[d];
        yln[((size_t)b * cL + l) * 192 + d] = yn * silu_f(zv);
    }
}

// ---------------------------------------------------------------- K8: out_proj GEMM, 4x4 register tile
__global__ __launch_bounds__(256) void k_outproj(const float* __restrict__ yln,
                                                 const float* __restrict__ w,
                                                 float* __restrict__ hout) {
    int bid = blockIdx.x;                  // B*3*64
    int lt0 = (bid & 63) * 64;
    int et = (bid >> 6) % 3;
    int b = bid / 192;
    int e0 = et * 64;
    __shared__ float sW[16][68];
    __shared__ float sI[16][68];
    int tid = threadIdx.x;
    int tl = tid & 15, te = tid >> 4;
    float acc[4][4];
#pragma unroll
    for (int i = 0; i < 4; i++)
#pragma unroll
        for (int j = 0; j < 4; j++) acc[i][j] = 0.f;
    for (int c0 = 0; c0 < 192; c0 += 16) {
#pragma unroll
        for (int q = 0; q < 4; q++) {
            int tt = tid + q * 256;
            int cc = tt & 15, ee = tt >> 4;
            sW[cc][ee] = w[(e0 + ee) * 192 + c0 + cc];
        }
#pragma unroll
        for (int q = 0; q < 4; q++) {
            int tt = tid + q * 256;
            int cc = tt & 15, lq = tt >> 4;   // 0..63 across 4 passes
            sI[cc][lq] = yln[((size_t)b * cL + lt0 + lq) * 192 + c0 + cc];
        }
        __syncthreads();
#pragma unroll
        for (int cc = 0; cc < 16; cc++) {
            float4 wv = *reinterpret_cast<const float4*>(&sW[cc][te * 4]);
            float4 iv = *reinterpret_cast<const float4*>(&sI[cc][tl * 4]);
            acc[0][0] = fmaf(wv.x, iv.x, acc[0][0]); acc[0][1] = fmaf(wv.x, iv.y, acc[0][1]);
            acc[0][2] = fmaf(wv.x, iv.z, acc[0][2]); acc[0][3] = fmaf(wv.x, iv.w, acc[0][3]);
            acc[1][0] = fmaf(wv.y, iv.x, acc[1][0]); acc[1][1] = fmaf(wv.y, iv.y, acc[1][1]);
            acc[1][2] = fmaf(wv.y, iv.z, acc[1][2]); acc[1][3] = fmaf(wv.y, iv.w, acc[1][3]);
            acc[2][0] = fmaf(wv.z, iv.x, acc[2][0]); acc[2][1] = fmaf(wv.z, iv.y, acc[2][1]);
            acc[2][2] = fmaf(wv.z, iv.z, acc[2][2]); acc[2][3] = fmaf(wv.z, iv.w, acc[2][3]);
            acc[3][0] = fmaf(wv.w, iv.x, acc[3][0]); acc[3][1] = fmaf(wv.w, iv.y, acc[3][1]);
            acc[3][2] = fmaf(wv.w, iv.z, acc[3][2]); acc[3][3] = fmaf(wv.w, iv.w, acc[3][3]);
        }
        __syncthreads();
    }
    int ebase = e0 + te * 4;
    int lbase = lt0 + tl * 4;
#pragma unroll
    for (int j = 0; j < 4; j++) {
        *reinterpret_cast<float4*>(&hout[((size_t)b * cL + lbase + j) * 192 + ebase]) =
            make_float4(acc[0][j], acc[1][j], acc[2][j], acc[3][j]);
    }
}

// ---------------------------------------------------------------- K9: ln2 + mamba mult -> merged (b,l,256)
__global__ __launch_bounds__(256) void k_ln2(const float* __restrict__ hout,
                                             const float* __restrict__ lowT,
                                             const float* __restrict__ l2s,
                                             const float* __restrict__ l2b,
                                             float* __restrict__ merged) {
    int bid = blockIdx.x;                  // B*1024
    int b = bid >> 10;
    int pg = bid & 1023;
    int tid = threadIdx.x;
    int wq = tid >> 6, lane = tid & 63;
    int l = pg * 4 + wq;
    float v[3];
    float s = 0.f, s2 = 0.f;
#pragma unroll
    for (int m = 0; m < 3; m++) {
        int d = lane + 64 * m;
        float t = hout[((size_t)b * cL + l) * 192 + d];
        v[m] = t;
        s += t;
        s2 += t * t;
    }
#pragma unroll
    for (int o = 1; o < 64; o <<= 1) {
        s += __shfl_xor(s, o);
        s2 += __shfl_xor(s2, o);
    }
    float mean = s / 192.f;
    float var = s2 / 192.f - mean * mean;
    float rstd = rsqrtf(var + 1e-5f);
    float lv = lowT[((size_t)b * cL + l) * 64 + lane];
    float* mp = merged + ((size_t)b * cL + l) * 256;
    mp[lane] = lv;
#pragma unroll
    for (int m = 0; m < 3; m++) {
        int d = lane + 64 * m;
        float hn = (v[m] - mean) * rstd * l2s[d] + l2b[d];
        mp[64 + d] = lv * hn;
    }
}

// ---------------------------------------------------------------- K10: inverse Haar + fused spatial-mean accumulation
__global__ __launch_bounds__(256) void k_iwt(const float* __restrict__ merged,
                                             float* __restrict__ ypre,
                                             float* __restrict__ pooled) {
    int idx = blockIdx.x * 256 + threadIdx.x;    // B*64*64*64 = 1,048,576
    int j = idx & 63, i = (idx >> 6) & 63, g = (idx >> 12) & 63, b = idx >> 18;
    const float4 mv = *reinterpret_cast<const float4*>(merged + ((size_t)b * cL + i * 64 + j) * 256 + g * 4);
    float m0 = mv.x, m1 = mv.y, m2 = mv.z, m3 = mv.w;
    float* yp = ypre + ((size_t)(b * 64 + g) * cH + 2 * i) * cW + 2 * j;
    float2 r0 = make_float2(0.5f * (m0 + m1 + m2 + m3), 0.5f * (m0 + m1 - m2 - m3));
    float2 r1 = make_float2(0.5f * (m0 - m1 + m2 - m3), 0.5f * (m0 - m1 - m2 + m3));
    *reinterpret_cast<float2*>(yp) = r0;
    *reinterpret_cast<float2*>(yp + cW) = r1;
    // fused pool: wave-uniform (b,g) -> wave reduce + 1 atomic per wave
    float ssum = r0.x + r0.y + r1.x + r1.y;
#pragma unroll
    for (int o = 1; o < 64; o <<= 1) ssum += __shfl_xor(ssum, o);
    if ((threadIdx.x & 63) == 0) atomicAdd(&pooled[b * 64 + g], ssum * (1.f / (cH * cW)));
}

// ---------------------------------------------------------------- K12: ECA conv1d + sigmoid
__global__ __launch_bounds__(256) void k_eca(const float* __restrict__ pooled,
                                             const float* __restrict__ w,
                                             float* __restrict__ att) {
    int t = threadIdx.x;                   // 256 = B*C
    int b = t >> 6, c = t & 63;
    float s = 0.f;
#pragma unroll
    for (int u = 0; u < 5; u++) {
        int cc = c + u - 2;
        if (cc >= 0 && cc < 64) s += w[u] * pooled[b * 64 + cc];
    }
    att[t] = 1.f / (1.f + __expf(-s));
}

// ---------------------------------------------------------------- K13: y*att + x
__global__ __launch_bounds__(256) void k_final(const float* __restrict__ ypre,
                                               const float* __restrict__ x,
                                               const float* __restrict__ att,
                                               float* __restrict__ out) {
    int idx = blockIdx.x * 256 + threadIdx.x;      // 1,048,576 float4s
    size_t base = (size_t)idx * 4;
    int bc = (int)(base >> 14);                    // /16384 = (b*64+c)
    float a = att[bc];
    float4 yv = *reinterpret_cast<const float4*>(ypre + base);
    float4 xv = *reinterpret_cast<const float4*>(x + base);
    float4 o;
    o.x = fmaf(yv.x, a, xv.x);
    o.y = fmaf(yv.y, a, xv.y);
    o.z = fmaf(yv.z, a, xv.z);
    o.w = fmaf(yv.w, a, xv.w);
    *reinterpret_cast<float4*>(out + base) = o;
}

// =================================================================
extern "C" void kernel_launch(void* const* d_in, const int* in_sizes, int n_in,
                              void* d_out, int out_size, void* d_ws, size_t ws_size,
                              hipStream_t stream) {
    const float* x    = (const float*)d_in[0];
    const float* wls  = (const float*)d_in[1];
    const float* whs  = (const float*)d_in[2];
    const float* lcw  = (const float*)d_in[3];
    const float* ipw  = (const float*)d_in[4];
    const float* dww  = (const float*)d_in[5];
    const float* dwb  = (const float*)d_in[6];
    const float* xpw  = (const float*)d_in[7];
    const float* dtw  = (const float*)d_in[8];
    const float* dtb  = (const float*)d_in[9];
    const float* alog = (const float*)d_in[10];
    const float* dss  = (const float*)d_in[11];
    const float* ons  = (const float*)d_in[12];
    const float* onb  = (const float*)d_in[13];
    const float* opw  = (const float*)d_in[14];
    const float* l2s  = (const float*)d_in[15];
    const float* l2b  = (const float*)d_in[16];
    const float* ecw  = (const float*)d_in[17];
    float* out = (float*)d_out;
    float* w = (float*)d_ws;

    // workspace layout (floats), total 27,656,192 = 105.5 MiB
    float* high   = w + 0;          // 3,145,728  (B*D*L)
    float* lraw   = w + 3145728;    // 1,048,576
    float* lowT   = w + 4194304;    // 1,048,576
    float* xbuf   = w + 5242880;    // 3,145,728
    float* zT     = w + 8388608;    // 3,145,728
    float* x1     = w + 11534336;   // 3,145,728
    float* u1     = w + 14680064;   // 3,145,728
    float* yacc   = w + 17825792;   // 3,145,728  (B*L*D)
    float* Sbuf   = w + 20971520;   // 6,291,456  (bk16 * NCH128 * 16n * 192d)
    float* Qbuf   = w + 27262976;   // 393,216    (bk16 * NCH128 * 192d)
    float* xdbl   = high;           // alias: high dead after in_proj
    float* yln    = xbuf;           // alias: xbuf dead after dwconv
    float* hout   = high;           // alias: xdbl dead after scan2
    float* merged = x1;             // alias: x1+u1 (6.3M contiguous) dead after scan2; need 4.19M
    float* ypre   = yacc;           // alias: yacc+Sbuf region dead after comb; need 4.19M
    float* pooled = lraw;           // alias: lraw dead after lowconv
    float* att    = lraw + 256;

    k_wt<<<4096, 256, 0, stream>>>(x, wls, whs, lraw, high);
    k_lowconv<<<256, 256, 0, stream>>>(lraw, lcw, lowT);
    k_inproj<<<1536, 256, 0, stream>>>(high, ipw, xbuf, zT);
    k_dwconv<<<768, 256, 0, stream>>>(xbuf, dww, dwb, x1, u1);
    k_xproj<<<1024, 256, 0, stream>>>(x1, u1, xpw, xdbl);
    hipMemsetAsync(yacc, 0, (size_t)cB * cL * cD * sizeof(float), stream);
    hipMemsetAsync(pooled, 0, 256 * sizeof(float), stream);
    k_scan1<<<2048, 192, 0, stream>>>(xdbl, x1, u1, dtw, dtb, alog, Qbuf, Sbuf);
    k_carryQ<<<192, 256, 0, stream>>>(alog, Qbuf, Sbuf);
    k_scan2<<<2048, 192, 0, stream>>>(xdbl, x1, u1, dtw, dtb, alog, dss, Sbuf, yacc);
    k_comb<<<4096, 256, 0, stream>>>(yacc, zT, ons, onb, yln);
    k_outproj<<<768, 256, 0, stream>>>(yln, opw, hout);
    k_ln2<<<4096, 256, 0, stream>>>(hout, lowT, l2s, l2b, merged);
    k_iwt<<<4096, 256, 0, stream>>>(merged, ypre, pooled);
    k_eca<<<1, 256, 0, stream>>>(pooled, ecw, att);
    k_final<<<4096, 256, 0, stream>>>(ypre, x, att, out);
}

// Round 18
// 374.602 us; speedup vs baseline: 1.0728x; 1.0728x over previous
//
#include <hip/hip_runtime.h>

constexpr int cB = 4, cC = 64, cH = 128, cW = 128;
constexpr int cL = 4096;   // 64*64
constexpr int cD = 192, cN = 16;
constexpr int NCH = 64, CHUNK = 64;   // cL = NCH*CHUNK

__device__ __forceinline__ float silu_f(float v) { return v / (1.f + __expf(-v)); }

// ---------------------------------------------------------------- K1: Haar DWT + scales
__global__ __launch_bounds__(256) void k_wt(const float* __restrict__ x,
                                            const float* __restrict__ wls,
                                            const float* __restrict__ whs,
                                            float* __restrict__ lraw,
                                            float* __restrict__ high) {
    int idx = blockIdx.x * 256 + threadIdx.x;          // B*C*L = 1,048,576
    int j = idx & 63, i = (idx >> 6) & 63, c = (idx >> 12) & 63, b = idx >> 18;
    const float* xp = x + (((size_t)(b * cC + c)) * cH + 2 * i) * cW + 2 * j;
    float x00 = xp[0], x01 = xp[1], x10 = xp[cW], x11 = xp[cW + 1];
    float s0 = 0.5f * (x00 + x01 + x10 + x11);
    float s1 = 0.5f * (x00 + x01 - x10 - x11);
    float s2 = 0.5f * (x00 - x01 + x10 - x11);
    float s3 = 0.5f * (x00 - x01 - x10 + x11);
    int l = i * 64 + j;
    lraw[(size_t)(b * cC + c) * cL + l] = s0 * wls[c];
    int ch = c * 3;
    high[(size_t)(b * cD + ch + 0) * cL + l] = s1 * whs[ch + 0];
    high[(size_t)(b * cD + ch + 1) * cL + l] = s2 * whs[ch + 1];
    high[(size_t)(b * cD + ch + 2) * cL + l] = s3 * whs[ch + 2];
}

// ---------------------------------------------------------------- K2: low 1x1 conv + silu -> (b,l,c), 4x4 register tile
__global__ __launch_bounds__(256) void k_lowconv(const float* __restrict__ lraw,
                                                 const float* __restrict__ w,
                                                 float* __restrict__ lowT) {
    int bid = blockIdx.x;                 // B*64
    int lt0 = (bid & 63) * 64;
    int b = bid >> 6;
    __shared__ float sW[16][68];
    __shared__ float sI[16][68];
    int tid = threadIdx.x;
    int tl = tid & 15, te = tid >> 4;
    float acc[4][4];
#pragma unroll
    for (int i = 0; i < 4; i++)
#pragma unroll
        for (int j = 0; j < 4; j++) acc[i][j] = 0.f;
    for (int c0 = 0; c0 < 64; c0 += 16) {
#pragma unroll
        for (int q = 0; q < 4; q++) {
            int tt = tid + q * 256;
            int cc = tt & 15, ee = tt >> 4;
            sW[cc][ee] = w[ee * 64 + c0 + cc];
        }
#pragma unroll
        for (int q = 0; q < 4; q++) {
            int tt = tid + q * 256;
            int ll = tt & 63, cc = tt >> 6;
            sI[cc][ll] = lraw[(size_t)(b * cC + c0 + cc) * cL + lt0 + ll];
        }
        __syncthreads();
#pragma unroll
        for (int cc = 0; cc < 16; cc++) {
            float4 wv = *reinterpret_cast<const float4*>(&sW[cc][te * 4]);
            float4 iv = *reinterpret_cast<const float4*>(&sI[cc][tl * 4]);
            acc[0][0] = fmaf(wv.x, iv.x, acc[0][0]); acc[0][1] = fmaf(wv.x, iv.y, acc[0][1]);
            acc[0][2] = fmaf(wv.x, iv.z, acc[0][2]); acc[0][3] = fmaf(wv.x, iv.w, acc[0][3]);
            acc[1][0] = fmaf(wv.y, iv.x, acc[1][0]); acc[1][1] = fmaf(wv.y, iv.y, acc[1][1]);
            acc[1][2] = fmaf(wv.y, iv.z, acc[1][2]); acc[1][3] = fmaf(wv.y, iv.w, acc[1][3]);
            acc[2][0] = fmaf(wv.z, iv.x, acc[2][0]); acc[2][1] = fmaf(wv.z, iv.y, acc[2][1]);
            acc[2][2] = fmaf(wv.z, iv.z, acc[2][2]); acc[2][3] = fmaf(wv.z, iv.w, acc[2][3]);
            acc[3][0] = fmaf(wv.w, iv.x, acc[3][0]); acc[3][1] = fmaf(wv.w, iv.y, acc[3][1]);
            acc[3][2] = fmaf(wv.w, iv.z, acc[3][2]); acc[3][3] = fmaf(wv.w, iv.w, acc[3][3]);
        }
        __syncthreads();
    }
    int ebase = te * 4;
    int lbase = lt0 + tl * 4;
#pragma unroll
    for (int j = 0; j < 4; j++) {
        float4 v = make_float4(silu_f(acc[0][j]), silu_f(acc[1][j]), silu_f(acc[2][j]), silu_f(acc[3][j]));
        *reinterpret_cast<float4*>(&lowT[((size_t)b * cL + lbase + j) * 64 + ebase]) = v;
    }
}

// ---------------------------------------------------------------- K3: in_proj GEMM 384x192, 4x4 register tile
__global__ __launch_bounds__(256) void k_inproj(const float* __restrict__ hi,
                                                const float* __restrict__ w,
                                                float* __restrict__ xout,
                                                float* __restrict__ zT) {
    int bid = blockIdx.x;                  // (b*64+lt)*6 + et
    int et = bid % 6;
    int blt = bid / 6;
    int lt0 = (blt & 63) * 64;
    int b = blt >> 6;
    int e0 = et * 64;
    __shared__ float sW[16][68];
    __shared__ float sI[16][68];
    int tid = threadIdx.x;
    int tl = tid & 15, te = tid >> 4;
    float acc[4][4];
#pragma unroll
    for (int i = 0; i < 4; i++)
#pragma unroll
        for (int j = 0; j < 4; j++) acc[i][j] = 0.f;
    for (int c0 = 0; c0 < 192; c0 += 16) {
#pragma unroll
        for (int q = 0; q < 4; q++) {
            int tt = tid + q * 256;
            int cc = tt & 15, ee = tt >> 4;
            sW[cc][ee] = w[(e0 + ee) * 192 + c0 + cc];
        }
#pragma unroll
        for (int q = 0; q < 4; q++) {
            int tt = tid + q * 256;
            int ll = tt & 63, cc = tt >> 6;
            sI[cc][ll] = hi[(size_t)(b * cD + c0 + cc) * cL + lt0 + ll];
        }
        __syncthreads();
#pragma unroll
        for (int cc = 0; cc < 16; cc++) {
            float4 wv = *reinterpret_cast<const float4*>(&sW[cc][te * 4]);
            float4 iv = *reinterpret_cast<const float4*>(&sI[cc][tl * 4]);
            acc[0][0] = fmaf(wv.x, iv.x, acc[0][0]); acc[0][1] = fmaf(wv.x, iv.y, acc[0][1]);
            acc[0][2] = fmaf(wv.x, iv.z, acc[0][2]); acc[0][3] = fmaf(wv.x, iv.w, acc[0][3]);
            acc[1][0] = fmaf(wv.y, iv.x, acc[1][0]); acc[1][1] = fmaf(wv.y, iv.y, acc[1][1]);
            acc[1][2] = fmaf(wv.y, iv.z, acc[1][2]); acc[1][3] = fmaf(wv.y, iv.w, acc[1][3]);
            acc[2][0] = fmaf(wv.z, iv.x, acc[2][0]); acc[2][1] = fmaf(wv.z, iv.y, acc[2][1]);
            acc[2][2] = fmaf(wv.z, iv.z, acc[2][2]); acc[2][3] = fmaf(wv.z, iv.w, acc[2][3]);
            acc[3][0] = fmaf(wv.w, iv.x, acc[3][0]); acc[3][1] = fmaf(wv.w, iv.y, acc[3][1]);
            acc[3][2] = fmaf(wv.w, iv.z, acc[3][2]); acc[3][3] = fmaf(wv.w, iv.w, acc[3][3]);
        }
        __syncthreads();
    }
    int ebase = e0 + te * 4;
    int lbase = lt0 + tl * 4;
    if (ebase < 192) {
#pragma unroll
        for (int i = 0; i < 4; i++) {
            *reinterpret_cast<float4*>(&xout[(size_t)(b * cD + ebase + i) * cL + lbase]) =
                make_float4(acc[i][0], acc[i][1], acc[i][2], acc[i][3]);
        }
    } else {
#pragma unroll
        for (int j = 0; j < 4; j++) {
            *reinterpret_cast<float4*>(&zT[((size_t)b * cL + lbase + j) * 192 + (ebase - 192)]) =
                make_float4(acc[0][j], acc[1][j], acc[2][j], acc[3][j]);
        }
    }
}

// ---------------------------------------------------------------- K4: dw conv 3x3 + bias + silu; emits x1 and transpose u1
__global__ __launch_bounds__(256) void k_dwconv(const float* __restrict__ xin,
                                                const float* __restrict__ w,
                                                const float* __restrict__ bias,
                                                float* __restrict__ x1,
                                                float* __restrict__ u1) {
    int bd = blockIdx.x;                   // B*D = 768
    int d = bd % cD;
    const float* xp = xin + (size_t)bd * cL;
    float wv[9];
#pragma unroll
    for (int t = 0; t < 9; t++) wv[t] = w[d * 9 + t];
    float bv = bias[d];
    __shared__ float sm[64][65];
    int tid = threadIdx.x;
#pragma unroll
    for (int q = 0; q < 16; q++) {
        int p = tid + q * 256;
        int i = p >> 6, j = p & 63;
        float acc = bv;
#pragma unroll
        for (int di = 0; di < 3; di++) {
            int ii = i + di - 1;
            if (ii < 0 || ii >= 64) continue;
#pragma unroll
            for (int dj = 0; dj < 3; dj++) {
                int jj = j + dj - 1;
                if (jj < 0 || jj >= 64) continue;
                acc = fmaf(wv[di * 3 + dj], xp[ii * 64 + jj], acc);
            }
        }
        sm[i][j] = silu_f(acc);
    }
    __syncthreads();
#pragma unroll
    for (int q = 0; q < 16; q++) {
        int p = tid + q * 256;
        x1[(size_t)bd * cL + p] = sm[p >> 6][p & 63];
        u1[(size_t)bd * cL + p] = sm[p & 63][p >> 6];
    }
}

// ---------------------------------------------------------------- K5: x_proj GEMM (38x192 per direction), 4x4 register tile
__global__ __launch_bounds__(256) void k_xproj(const float* __restrict__ x1,
                                               const float* __restrict__ u1,
                                               const float* __restrict__ xpw,
                                               float* __restrict__ xdbl) {
    int bid = blockIdx.x;                 // B*4*64
    int lt0 = (bid & 63) * 64;
    int k = (bid >> 6) & 3;
    int b = bid >> 8;
    const float* src = (k & 1) ? u1 : x1;
    bool rev = (k >= 2);
    __shared__ float sW[16][68];
    __shared__ float sI[16][68];
    int tid = threadIdx.x;
    int tl = tid & 15, te = tid >> 4;
    float acc[4][4];
#pragma unroll
    for (int i = 0; i < 4; i++)
#pragma unroll
        for (int j = 0; j < 4; j++) acc[i][j] = 0.f;
    for (int c0 = 0; c0 < 192; c0 += 16) {
#pragma unroll
        for (int q = 0; q < 4; q++) {
            int tt = tid + q * 256;
            int cc = tt & 15, ee = tt >> 4;
            sW[cc][ee] = (ee < 38) ? xpw[(k * 38 + ee) * 192 + c0 + cc] : 0.f;
        }
#pragma unroll
        for (int q = 0; q < 4; q++) {
            int tt = tid + q * 256;
            int ll = tt & 63, cc = tt >> 6;
            int l = lt0 + ll;
            int lm = rev ? (cL - 1 - l) : l;
            sI[cc][ll] = src[(size_t)(b * cD + c0 + cc) * cL + lm];
        }
        __syncthreads();
#pragma unroll
        for (int cc = 0; cc < 16; cc++) {
            float4 wv = *reinterpret_cast<const float4*>(&sW[cc][te * 4]);
            float4 iv = *reinterpret_cast<const float4*>(&sI[cc][tl * 4]);
            acc[0][0] = fmaf(wv.x, iv.x, acc[0][0]); acc[0][1] = fmaf(wv.x, iv.y, acc[0][1]);
            acc[0][2] = fmaf(wv.x, iv.z, acc[0][2]); acc[0][3] = fmaf(wv.x, iv.w, acc[0][3]);
            acc[1][0] = fmaf(wv.y, iv.x, acc[1][0]); acc[1][1] = fmaf(wv.y, iv.y, acc[1][1]);
            acc[1][2] = fmaf(wv.y, iv.z, acc[1][2]); acc[1][3] = fmaf(wv.y, iv.w, acc[1][3]);
            acc[2][0] = fmaf(wv.z, iv.x, acc[2][0]); acc[2][1] = fmaf(wv.z, iv.y, acc[2][1]);
            acc[2][2] = fmaf(wv.z, iv.z, acc[2][2]); acc[2][3] = fmaf(wv.z, iv.w, acc[2][3]);
            acc[3][0] = fmaf(wv.w, iv.x, acc[3][0]); acc[3][1] = fmaf(wv.w, iv.y, acc[3][1]);
            acc[3][2] = fmaf(wv.w, iv.z, acc[3][2]); acc[3][3] = fmaf(wv.w, iv.w, acc[3][3]);
        }
        __syncthreads();
    }
    int lbase = lt0 + tl * 4;
#pragma unroll
    for (int i = 0; i < 4; i++) {
        int e = te * 4 + i;
        if (e < 38) {
            *reinterpret_cast<float4*>(&xdbl[(size_t)((b * 4 + k) * 38 + e) * cL + lbase]) =
                make_float4(acc[i][0], acc[i][1], acc[i][2], acc[i][3]);
        }
    }
}

// ---------------------------------------------------------------- K6a: scan pass 1 — lean: u in regs, dbuf LDS for B/dt
__global__ __launch_bounds__(192) void k_scan1(const float* __restrict__ xdbl,
                                               const float* __restrict__ x1,
                                               const float* __restrict__ u1,
                                               const float* __restrict__ dtw,
                                               const float* __restrict__ dtb,
                                               const float* __restrict__ alog,
                                               float* __restrict__ P,
                                               float* __restrict__ S) {
    int bid = blockIdx.x;                  // bk*NCH + ch, 1024 blocks
    int ch = bid % NCH;
    int bk = bid / NCH;
    int k = bk & 3, b = bk >> 2;
    int tid = threadIdx.x;
    int d = tid;                           // 0..191
    float Av2[16], h[16];
#pragma unroll
    for (int j = 0; j < 16; j++) {
        Av2[j] = -__expf(alog[(k * 192 + d) * 16 + j]) * 1.44269504088896f;
        h[j] = 0.f;
    }
    float dtbv = dtb[k * 192 + d];
    float dtwv[6];
#pragma unroll
    for (int r = 0; r < 6; r++) dtwv[r] = dtw[(k * 192 + d) * 6 + r];
    const float* dtrows = xdbl + (size_t)(bk * 38) * cL;
    const float* Brow = xdbl + (size_t)(bk * 38 + 6) * cL;
    const float* ubase = ((k & 1) ? u1 : x1) + ((size_t)b * cD + d) * cL;
    bool rev = (k >= 2);

    __shared__ float sB[2][16][16];   // [l][n]
    __shared__ float sdt[2][16][8];   // [l][r]

    int rowA = tid >> 4, colA = tid & 15;
    int p0 = ch * CHUNK;

    // stage tile 0
    for (int idx = tid; idx < 256; idx += 192)
        sB[0][idx & 15][idx >> 4] = Brow[(size_t)(idx >> 4) * cL + p0 + (idx & 15)];
    if (tid < 96) sdt[0][colA][rowA] = dtrows[(size_t)rowA * cL + p0 + colA];

    float Q = 0.f;
    int cur = 0;
    for (int t0 = p0; t0 < p0 + CHUNK; t0 += 16) {
        __syncthreads();
        if (t0 + 16 < p0 + CHUNK) {
            int t1 = t0 + 16;
            for (int idx = tid; idx < 256; idx += 192)
                sB[cur ^ 1][idx & 15][idx >> 4] = Brow[(size_t)(idx >> 4) * cL + t1 + (idx & 15)];
            if (tid < 96) sdt[cur ^ 1][colA][rowA] = dtrows[(size_t)rowA * cL + t1 + colA];
        }
        // u tile -> registers (contiguous 64B)
        float uvals[16];
        {
            const float* up = rev ? (ubase + (cL - 16 - t0)) : (ubase + t0);
#pragma unroll
            for (int q = 0; q < 4; q++)
                *reinterpret_cast<float4*>(&uvals[q * 4]) = *reinterpret_cast<const float4*>(up + q * 4);
        }
#pragma unroll
        for (int l = 0; l < 16; l++) {
            float acc = dtbv;
#pragma unroll
            for (int r = 0; r < 6; r++) acc = fmaf(dtwv[r], sdt[cur][l][r], acc);
            float sp = fmaxf(acc, 0.f) + __logf(1.f + __expf(-fabsf(acc)));
            Q += sp;
            float uv = rev ? uvals[15 - l] : uvals[l];
            float duB = sp * uv;
            float Bv[16];
            *reinterpret_cast<float4*>(&Bv[0])  = *reinterpret_cast<const float4*>(&sB[cur][l][0]);
            *reinterpret_cast<float4*>(&Bv[4])  = *reinterpret_cast<const float4*>(&sB[cur][l][4]);
            *reinterpret_cast<float4*>(&Bv[8])  = *reinterpret_cast<const float4*>(&sB[cur][l][8]);
            *reinterpret_cast<float4*>(&Bv[12]) = *reinterpret_cast<const float4*>(&sB[cur][l][12]);
#pragma unroll
            for (int j = 0; j < 16; j++)
                h[j] = fmaf(h[j], exp2f(sp * Av2[j]), duB * Bv[j]);
        }
        cur ^= 1;
    }
    size_t base = (size_t)bid * 16 * 192 + d;
#pragma unroll
    for (int j = 0; j < 16; j++) {
        P[base + (size_t)j * 192] = exp2f(Av2[j] * Q);
        S[base + (size_t)j * 192] = h[j];
    }
}

// ---------------------------------------------------------------- K6b: carry prefix over chunks (in-place in S)
__global__ __launch_bounds__(256) void k_carry(const float* __restrict__ P,
                                               float* __restrict__ S) {
    int gid = blockIdx.x * 256 + threadIdx.x;  // 49152 = 16bk * 16n * 192d
    int d = gid % 192;
    int n = (gid / 192) & 15;
    int bk = gid / 3072;
    float h = 0.f;
    for (int c = 0; c < NCH; c++) {
        size_t idx = ((size_t)(bk * NCH + c) * 16 + n) * 192 + d;
        h = fmaf(P[idx], h, S[idx]);
        S[idx] = h;
    }
}

// ---------------------------------------------------------------- K6c: scan pass 2 — lean replay, y -> atomic combine
__global__ __launch_bounds__(192) void k_scan2(const float* __restrict__ xdbl,
                                               const float* __restrict__ x1,
                                               const float* __restrict__ u1,
                                               const float* __restrict__ dtw,
                                               const float* __restrict__ dtb,
                                               const float* __restrict__ alog,
                                               const float* __restrict__ dss,
                                               const float* __restrict__ S,
                                               float* __restrict__ yacc) {
    int bid = blockIdx.x;
    int ch = bid % NCH;
    int bk = bid / NCH;
    int k = bk & 3, b = bk >> 2;
    int tid = threadIdx.x;
    int d = tid;
    float Av2[16], h[16];
#pragma unroll
    for (int j = 0; j < 16; j++) {
        Av2[j] = -__expf(alog[(k * 192 + d) * 16 + j]) * 1.44269504088896f;
        h[j] = (ch == 0) ? 0.f : S[((size_t)(bk * NCH + ch - 1) * 16 + j) * 192 + d];
    }
    float Dv = dss[k * 192 + d];
    float dtbv = dtb[k * 192 + d];
    float dtwv[6];
#pragma unroll
    for (int r = 0; r < 6; r++) dtwv[r] = dtw[(k * 192 + d) * 6 + r];
    const float* dtrows = xdbl + (size_t)(bk * 38) * cL;
    const float* Brow = xdbl + (size_t)(bk * 38 + 6) * cL;
    const float* Crow = xdbl + (size_t)(bk * 38 + 22) * cL;
    const float* ubase = ((k & 1) ? u1 : x1) + ((size_t)b * cD + d) * cL;
    bool rev = (k >= 2);

    __shared__ float sB[2][16][16];
    __shared__ float sC[2][16][16];
    __shared__ float sdt[2][16][8];

    int rowA = tid >> 4, colA = tid & 15;
    int p0 = ch * CHUNK;

    for (int idx = tid; idx < 256; idx += 192) {
        sB[0][idx & 15][idx >> 4] = Brow[(size_t)(idx >> 4) * cL + p0 + (idx & 15)];
        sC[0][idx & 15][idx >> 4] = Crow[(size_t)(idx >> 4) * cL + p0 + (idx & 15)];
    }
    if (tid < 96) sdt[0][colA][rowA] = dtrows[(size_t)rowA * cL + p0 + colA];

    int cur = 0;
    for (int t0 = p0; t0 < p0 + CHUNK; t0 += 16) {
        __syncthreads();
        if (t0 + 16 < p0 + CHUNK) {
            int t1 = t0 + 16;
            for (int idx = tid; idx < 256; idx += 192) {
                sB[cur ^ 1][idx & 15][idx >> 4] = Brow[(size_t)(idx >> 4) * cL + t1 + (idx & 15)];
                sC[cur ^ 1][idx & 15][idx >> 4] = Crow[(size_t)(idx >> 4) * cL + t1 + (idx & 15)];
            }
            if (tid < 96) sdt[cur ^ 1][colA][rowA] = dtrows[(size_t)rowA * cL + t1 + colA];
        }
        float uvals[16];
        {
            const float* up = rev ? (ubase + (cL - 16 - t0)) : (ubase + t0);
#pragma unroll
            for (int q = 0; q < 4; q++)
                *reinterpret_cast<float4*>(&uvals[q * 4]) = *reinterpret_cast<const float4*>(up + q * 4);
        }
#pragma unroll
        for (int l = 0; l < 16; l++) {
            float acc = dtbv;
#pragma unroll
            for (int r = 0; r < 6; r++) acc = fmaf(dtwv[r], sdt[cur][l][r], acc);
            float sp = fmaxf(acc, 0.f) + __logf(1.f + __expf(-fabsf(acc)));
            float uv = rev ? uvals[15 - l] : uvals[l];
            float duB = sp * uv;
            float Bv[16], Cv[16];
            *reinterpret_cast<float4*>(&Bv[0])  = *reinterpret_cast<const float4*>(&sB[cur][l][0]);
            *reinterpret_cast<float4*>(&Bv[4])  = *reinterpret_cast<const float4*>(&sB[cur][l][4]);
            *reinterpret_cast<float4*>(&Bv[8])  = *reinterpret_cast<const float4*>(&sB[cur][l][8]);
            *reinterpret_cast<float4*>(&Bv[12]) = *reinterpret_cast<const float4*>(&sB[cur][l][12]);
            *reinterpret_cast<float4*>(&Cv[0])  = *reinterpret_cast<const float4*>(&sC[cur][l][0]);
            *reinterpret_cast<float4*>(&Cv[4])  = *reinterpret_cast<const float4*>(&sC[cur][l][4]);
            *reinterpret_cast<float4*>(&Cv[8])  = *reinterpret_cast<const float4*>(&sC[cur][l][8]);
            *reinterpret_cast<float4*>(&Cv[12]) = *reinterpret_cast<const float4*>(&sC[cur][l][12]);
            float yA = 0.f, yB = 0.f;
#pragma unroll
            for (int j = 0; j < 8; j++) {
                h[j] = fmaf(h[j], exp2f(sp * Av2[j]), duB * Bv[j]);
                yA = fmaf(h[j], Cv[j], yA);
            }
#pragma unroll
            for (int j = 8; j < 16; j++) {
                h[j] = fmaf(h[j], exp2f(sp * Av2[j]), duB * Bv[j]);
                yB = fmaf(h[j], Cv[j], yB);
            }
            float y = yA + yB + uv * Dv;
            int lg = t0 + l;
            int lm;
            if (k == 0) lm = lg;
            else if (k == 1) lm = (lg & 63) * 64 + (lg >> 6);
            else if (k == 2) lm = cL - 1 - lg;
            else { int qq = cL - 1 - lg; lm = (qq & 63) * 64 + (qq >> 6); }
            atomicAdd(&yacc[((size_t)b * cL + lm) * 192 + d], y);
        }
        cur ^= 1;
    }
}

// ---------------------------------------------------------------- K7: out_norm LN + silu(z)
__global__ __launch_bounds__(256) void k_comb(const float* __restrict__ yacc,
                                              const float* __restrict__ zT,
                                              const float* __restrict__ ons,
                                              const float* __restrict__ onb,
                                              float* __restrict__ yln) {
    int bid = blockIdx.x;                  // B*1024
    int b = bid >> 10;
    int pg = bid & 1023;
    int tid = threadIdx.x;
    int wq = tid >> 6, lane = tid & 63;
    int l = pg * 4 + wq;
    float v[3];
    float s = 0.f, s2 = 0.f;
#pragma unroll
    for (int m = 0; m < 3; m++) {
        int d = lane + 64 * m;
        float t = yacc[((size_t)b * cL + l) * 192 + d];
        v[m] = t;
        s += t;
        s2 += t * t;
    }
#pragma unroll
    for (int o = 1; o < 64; o <<= 1) {
        s += __shfl_xor(s, o);
        s2 += __shfl_xor(s2, o);
    }
    float mean = s / 192.f;
    float var = s2 / 192.f - mean * mean;
    float rstd = rsqrtf(var + 1e-5f);
#pragma unroll
    for (int m = 0; m < 3; m++) {
        int d = lane + 64 * m;
        float zv = zT[((size_t)b * cL + l) * 192 + d];
        float yn = (v[m] - mean) * rstd * ons[d] + onb[d];
        yln[((size_t)b * cL + l) * 192 + d] = yn * silu_f(zv);
    }
}

// ---------------------------------------------------------------- K8: out_proj GEMM, 4x4 register tile
__global__ __launch_bounds__(256) void k_outproj(const float* __restrict__ yln,
                                                 const float* __restrict__ w,
                                                 float* __restrict__ hout) {
    int bid = blockIdx.x;                  // B*3*64
    int lt0 = (bid & 63) * 64;
    int et = (bid >> 6) % 3;
    int b = bid / 192;
    int e0 = et * 64;
    __shared__ float sW[16][68];
    __shared__ float sI[16][68];
    int tid = threadIdx.x;
    int tl = tid & 15, te = tid >> 4;
    float acc[4][4];
#pragma unroll
    for (int i = 0; i < 4; i++)
#pragma unroll
        for (int j = 0; j < 4; j++) acc[i][j] = 0.f;
    for (int c0 = 0; c0 < 192; c0 += 16) {
#pragma unroll
        for (int q = 0; q < 4; q++) {
            int tt = tid + q * 256;
            int cc = tt & 15, ee = tt >> 4;
            sW[cc][ee] = w[(e0 + ee) * 192 + c0 + cc];
        }
#pragma unroll
        for (int q = 0; q < 4; q++) {
            int tt = tid + q * 256;
            int cc = tt & 15, lq = tt >> 4;   // 0..63 across 4 passes
            sI[cc][lq] = yln[((size_t)b * cL + lt0 + lq) * 192 + c0 + cc];
        }
        __syncthreads();
#pragma unroll
        for (int cc = 0; cc < 16; cc++) {
            float4 wv = *reinterpret_cast<const float4*>(&sW[cc][te * 4]);
            float4 iv = *reinterpret_cast<const float4*>(&sI[cc][tl * 4]);
            acc[0][0] = fmaf(wv.x, iv.x, acc[0][0]); acc[0][1] = fmaf(wv.x, iv.y, acc[0][1]);
            acc[0][2] = fmaf(wv.x, iv.z, acc[0][2]); acc[0][3] = fmaf(wv.x, iv.w, acc[0][3]);
            acc[1][0] = fmaf(wv.y, iv.x, acc[1][0]); acc[1][1] = fmaf(wv.y, iv.y, acc[1][1]);
            acc[1][2] = fmaf(wv.y, iv.z, acc[1][2]); acc[1][3] = fmaf(wv.y, iv.w, acc[1][3]);
            acc[2][0] = fmaf(wv.z, iv.x, acc[2][0]); acc[2][1] = fmaf(wv.z, iv.y, acc[2][1]);
            acc[2][2] = fmaf(wv.z, iv.z, acc[2][2]); acc[2][3] = fmaf(wv.z, iv.w, acc[2][3]);
            acc[3][0] = fmaf(wv.w, iv.x, acc[3][0]); acc[3][1] = fmaf(wv.w, iv.y, acc[3][1]);
            acc[3][2] = fmaf(wv.w, iv.z, acc[3][2]); acc[3][3] = fmaf(wv.w, iv.w, acc[3][3]);
        }
        __syncthreads();
    }
    int ebase = e0 + te * 4;
    int lbase = lt0 + tl * 4;
#pragma unroll
    for (int j = 0; j < 4; j++) {
        *reinterpret_cast<float4*>(&hout[((size_t)b * cL + lbase + j) * 192 + ebase]) =
            make_float4(acc[0][j], acc[1][j], acc[2][j], acc[3][j]);
    }
}

// ---------------------------------------------------------------- K9: ln2 + mamba mult -> merged (b,l,256)
__global__ __launch_bounds__(256) void k_ln2(const float* __restrict__ hout,
                                             const float* __restrict__ lowT,
                                             const float* __restrict__ l2s,
                                             const float* __restrict__ l2b,
                                             float* __restrict__ merged) {
    int bid = blockIdx.x;                  // B*1024
    int b = bid >> 10;
    int pg = bid & 1023;
    int tid = threadIdx.x;
    int wq = tid >> 6, lane = tid & 63;
    int l = pg * 4 + wq;
    float v[3];
    float s = 0.f, s2 = 0.f;
#pragma unroll
    for (int m = 0; m < 3; m++) {
        int d = lane + 64 * m;
        float t = hout[((size_t)b * cL + l) * 192 + d];
        v[m] = t;
        s += t;
        s2 += t * t;
    }
#pragma unroll
    for (int o = 1; o < 64; o <<= 1) {
        s += __shfl_xor(s, o);
        s2 += __shfl_xor(s2, o);
    }
    float mean = s / 192.f;
    float var = s2 / 192.f - mean * mean;
    float rstd = rsqrtf(var + 1e-5f);
    float lv = lowT[((size_t)b * cL + l) * 64 + lane];
    float* mp = merged + ((size_t)b * cL + l) * 256;
    mp[lane] = lv;
#pragma unroll
    for (int m = 0; m < 3; m++) {
        int d = lane + 64 * m;
        float hn = (v[m] - mean) * rstd * l2s[d] + l2b[d];
        mp[64 + d] = lv * hn;
    }
}

// ---------------------------------------------------------------- K10: inverse Haar
__global__ __launch_bounds__(256) void k_iwt(const float* __restrict__ merged,
                                             float* __restrict__ ypre) {
    int idx = blockIdx.x * 256 + threadIdx.x;    // B*64*64*64 = 1,048,576
    int j = idx & 63, i = (idx >> 6) & 63, g = (idx >> 12) & 63, b = idx >> 18;
    const float4 mv = *reinterpret_cast<const float4*>(merged + ((size_t)b * cL + i * 64 + j) * 256 + g * 4);
    float m0 = mv.x, m1 = mv.y, m2 = mv.z, m3 = mv.w;
    float* yp = ypre + ((size_t)(b * 64 + g) * cH + 2 * i) * cW + 2 * j;
    float2 r0 = make_float2(0.5f * (m0 + m1 + m2 + m3), 0.5f * (m0 + m1 - m2 - m3));
    float2 r1 = make_float2(0.5f * (m0 - m1 + m2 - m3), 0.5f * (m0 - m1 - m2 + m3));
    *reinterpret_cast<float2*>(yp) = r0;
    *reinterpret_cast<float2*>(yp + cW) = r1;
}

// ---------------------------------------------------------------- K11: spatial mean per (b,g)
__global__ __launch_bounds__(256) void k_pool(const float* __restrict__ ypre,
                                              float* __restrict__ pooled) {
    int bg = blockIdx.x;                   // 256
    const float* p = ypre + (size_t)bg * (cH * cW);
    float s = 0.f;
    for (int t = threadIdx.x; t < cH * cW; t += 256) s += p[t];
#pragma unroll
    for (int o = 1; o < 64; o <<= 1) s += __shfl_xor(s, o);
    __shared__ float red[4];
    if ((threadIdx.x & 63) == 0) red[threadIdx.x >> 6] = s;
    __syncthreads();
    if (threadIdx.x == 0) pooled[bg] = (red[0] + red[1] + red[2] + red[3]) * (1.f / (cH * cW));
}

// ---------------------------------------------------------------- K12: ECA conv1d + sigmoid
__global__ __launch_bounds__(256) void k_eca(const float* __restrict__ pooled,
                                             const float* __restrict__ w,
                                             float* __restrict__ att) {
    int t = threadIdx.x;                   // 256 = B*C
    int b = t >> 6, c = t & 63;
    float s = 0.f;
#pragma unroll
    for (int u = 0; u < 5; u++) {
        int cc = c + u - 2;
        if (cc >= 0 && cc < 64) s += w[u] * pooled[b * 64 + cc];
    }
    att[t] = 1.f / (1.f + __expf(-s));
}

// ---------------------------------------------------------------- K13: y*att + x
__global__ __launch_bounds__(256) void k_final(const float* __restrict__ ypre,
                                               const float* __restrict__ x,
                                               const float* __restrict__ att,
                                               float* __restrict__ out) {
    int idx = blockIdx.x * 256 + threadIdx.x;      // 1,048,576 float4s
    size_t base = (size_t)idx * 4;
    int bc = (int)(base >> 14);                    // /16384 = (b*64+c)
    float a = att[bc];
    float4 yv = *reinterpret_cast<const float4*>(ypre + base);
    float4 xv = *reinterpret_cast<const float4*>(x + base);
    float4 o;
    o.x = fmaf(yv.x, a, xv.x);
    o.y = fmaf(yv.y, a, xv.y);
    o.z = fmaf(yv.z, a, xv.z);
    o.w = fmaf(yv.w, a, xv.w);
    *reinterpret_cast<float4*>(out + base) = o;
}

// =================================================================
extern "C" void kernel_launch(void* const* d_in, const int* in_sizes, int n_in,
                              void* d_out, int out_size, void* d_ws, size_t ws_size,
                              hipStream_t stream) {
    const float* x    = (const float*)d_in[0];
    const float* wls  = (const float*)d_in[1];
    const float* whs  = (const float*)d_in[2];
    const float* lcw  = (const float*)d_in[3];
    const float* ipw  = (const float*)d_in[4];
    const float* dww  = (const float*)d_in[5];
    const float* dwb  = (const float*)d_in[6];
    const float* xpw  = (const float*)d_in[7];
    const float* dtw  = (const float*)d_in[8];
    const float* dtb  = (const float*)d_in[9];
    const float* alog = (const float*)d_in[10];
    const float* dss  = (const float*)d_in[11];
    const float* ons  = (const float*)d_in[12];
    const float* onb  = (const float*)d_in[13];
    const float* opw  = (const float*)d_in[14];
    const float* l2s  = (const float*)d_in[15];
    const float* l2b  = (const float*)d_in[16];
    const float* ecw  = (const float*)d_in[17];
    float* out = (float*)d_out;
    float* w = (float*)d_ws;

    // workspace layout (floats), total 24,117,248 = 92 MiB
    float* high   = w + 0;          // 3,145,728  (B*D*L)
    float* lraw   = w + 3145728;    // 1,048,576
    float* lowT   = w + 4194304;    // 1,048,576
    float* xbuf   = w + 5242880;    // 3,145,728
    float* zT     = w + 8388608;    // 3,145,728
    float* x1     = w + 11534336;   // 3,145,728
    float* u1     = w + 14680064;   // 3,145,728
    float* yacc   = w + 17825792;   // 3,145,728  (B*L*D)
    float* Sbuf   = w + 20971520;   // 3,145,728  (bk*NCH*16n*192d)
    float* xdbl   = high;           // alias: high dead after in_proj
    float* Pbuf   = xbuf;           // alias: xbuf dead after dwconv (3,145,728 exactly)
    float* yln    = xbuf;           // alias: P dead after carry; yln written after scan2
    float* hout   = high;           // alias: xdbl dead after scan2
    float* merged = x1;             // alias: x1+u1 (6.3M contiguous) dead after scan2; need 4.19M
    float* ypre   = yacc;           // alias: yacc(3.1M)+Sbuf(3.1M) dead after comb; need 4.19M
    float* pooled = lraw;           // alias: lraw dead after lowconv
    float* att    = lraw + 256;

    k_wt<<<4096, 256, 0, stream>>>(x, wls, whs, lraw, high);
    k_lowconv<<<256, 256, 0, stream>>>(lraw, lcw, lowT);
    k_inproj<<<1536, 256, 0, stream>>>(high, ipw, xbuf, zT);
    k_dwconv<<<768, 256, 0, stream>>>(xbuf, dww, dwb, x1, u1);
    k_xproj<<<1024, 256, 0, stream>>>(x1, u1, xpw, xdbl);
    hipMemsetAsync(yacc, 0, (size_t)cB * cL * cD * sizeof(float), stream);
    k_scan1<<<1024, 192, 0, stream>>>(xdbl, x1, u1, dtw, dtb, alog, Pbuf, Sbuf);
    k_carry<<<192, 256, 0, stream>>>(Pbuf, Sbuf);
    k_scan2<<<1024, 192, 0, stream>>>(xdbl, x1, u1, dtw, dtb, alog, dss, Sbuf, yacc);
    k_comb<<<4096, 256, 0, stream>>>(yacc, zT, ons, onb, yln);
    k_outproj<<<768, 256, 0, stream>>>(yln, opw, hout);
    k_ln2<<<4096, 256, 0, stream>>>(hout, lowT, l2s, l2b, merged);
    k_iwt<<<4096, 256, 0, stream>>>(merged, ypre);
    k_pool<<<256, 256, 0, stream>>>(ypre, pooled);
    k_eca<<<1, 256, 0, stream>>>(pooled, ecw, att);
    k_final<<<4096, 256, 0, stream>>>(ypre, x, att, out);
}